// Round 1
// baseline (9462.996 us; speedup 1.0000x reference)
//
#include <hip/hip_runtime.h>
#include <math.h>

#define B_    2
#define C_    1024
#define N_    80
#define D_    3074
#define DFF_  2048
#define OD_   1026      // C+2
#define QKV_  9222      // 3*D
#define M_    160       // B*N token rows
#define EPS_  1e-5f

// ---------------------------------------------------------------- reductions
__device__ inline float wave_sum(float v) {
#pragma unroll
    for (int off = 32; off > 0; off >>= 1) v += __shfl_down(v, off, 64);
    return v;
}

// reduce s and s2 across a 256-thread block; results broadcast to all threads
__device__ inline void block_reduce_2(float& s, float& s2, float* red) {
    int tid = threadIdx.x;
    int lane = tid & 63, wid = tid >> 6;
    s = wave_sum(s);
    s2 = wave_sum(s2);
    if (lane == 0) { red[wid] = s; red[4 + wid] = s2; }
    __syncthreads();
    if (tid == 0) {
        red[8] = red[0] + red[1] + red[2] + red[3];
        red[9] = red[4] + red[5] + red[6] + red[7];
    }
    __syncthreads();
    s = red[8]; s2 = red[9];
}

// ---------------------------------------------------------------- bilinear
// jax.image.resize bilinear 14->224, sampled at integer pixel p in [0,223]:
// src coord = (p+0.5)/16 - 0.5, clamped to [0,13] (edge renormalization ==
// clamp-to-edge for in-range samples).
__device__ inline void bilin_setup(int p, int& i0, int& i1, float& t) {
    float s = (p + 0.5f) * 0.0625f - 0.5f;
    s = fminf(fmaxf(s, 0.0f), 13.0f);
    i0 = (int)s;
    t = s - (float)i0;
    i1 = min(i0 + 1, 13);
}

__device__ inline float bilin_tap(const float* f, int y0, int y1, float ty,
                                  int x0, int x1, float tx) {
    float a = f[y0 * 14 + x0], b = f[y0 * 14 + x1];
    float c = f[y1 * 14 + x0], d = f[y1 * 14 + x1];
    return (1.f - ty) * ((1.f - tx) * a + tx * b) + ty * ((1.f - tx) * c + tx * d);
}

// ---------------------------------------------------------------- K0: align
__global__ __launch_bounds__(128) void align_kernel(const int* __restrict__ prev_b,
                                                    const int* __restrict__ first_b,
                                                    int* __restrict__ fb_al) {
    int b = blockIdx.x;
    int tid = threadIdx.x;
    __shared__ int dist[N_];
    __shared__ int bestIdx;
    if (tid < N_) {
        int s = 0;
        for (int j = 0; j < N_; ++j) {
            int src = (j - tid) % N_;
            if (src < 0) src += N_;
            int dy = prev_b[(b * N_ + j) * 2] - first_b[(b * N_ + src) * 2];
            int dx = prev_b[(b * N_ + j) * 2 + 1] - first_b[(b * N_ + src) * 2 + 1];
            s += abs(dy) + abs(dx);
        }
        dist[tid] = s;
    }
    __syncthreads();
    if (tid == 0) {
        int best = 0, bd = dist[0];
        for (int i = 1; i < N_; ++i)
            if (dist[i] < bd) { bd = dist[i]; best = i; }
        bestIdx = best;
    }
    __syncthreads();
    if (tid < N_) {
        int src = (tid - bestIdx) % N_;
        if (src < 0) src += N_;
        fb_al[(b * N_ + tid) * 2]     = first_b[(b * N_ + src) * 2];
        fb_al[(b * N_ + tid) * 2 + 1] = first_b[(b * N_ + src) * 2 + 1];
    }
}

// -------------------------------------------------- K1: pre_q/first_q gather
__global__ __launch_bounds__(256) void gather_init_kernel(
        const float* __restrict__ pre_f, const float* __restrict__ first_f,
        const int* __restrict__ prev_b, const int* __restrict__ fb_al,
        float* __restrict__ pre_q, float* __restrict__ first_q,
        float* __restrict__ curr) {
    int m = blockIdx.x;          // 0..159
    int b = m / N_;
    int tid = threadIdx.x;
    int py = prev_b[m * 2], px = prev_b[m * 2 + 1];
    int fy = fb_al[m * 2], fx = fb_al[m * 2 + 1];
    int py0, py1, px0, px1, fy0, fy1, fx0, fx1;
    float pty, ptx, fty, ftx;
    bilin_setup(py, py0, py1, pty);
    bilin_setup(px, px0, px1, ptx);
    bilin_setup(fy, fy0, fy1, fty);
    bilin_setup(fx, fx0, fx1, ftx);
    for (int c = tid; c < C_; c += 256) {
        const float* fp = pre_f + (size_t)(b * C_ + c) * 196;
        const float* ff = first_f + (size_t)(b * C_ + c) * 196;
        pre_q[(size_t)m * C_ + c]   = bilin_tap(fp, py0, py1, pty, px0, px1, ptx);
        first_q[(size_t)m * C_ + c] = bilin_tap(ff, fy0, fy1, fty, fx0, fx1, ftx);
    }
    if (tid < 2) curr[m * 2 + tid] = (float)prev_b[m * 2 + tid];
}

// -------------------------------------------------- K2: tokens = LN(cat)+pe
__global__ __launch_bounds__(256) void tokens_kernel(
        const float* __restrict__ curr_f, const float* __restrict__ pre_q,
        const float* __restrict__ first_q, const float* __restrict__ curr,
        const float* __restrict__ ln_g, const float* __restrict__ ln_b,
        float* __restrict__ tokens) {
    int m = blockIdx.x;
    int b = m / N_;
    int n = m % N_;
    int tid = threadIdx.x;
    __shared__ float bf[C_];
    __shared__ float red[10];

    float cy = curr[m * 2], cx = curr[m * 2 + 1];
    int iy = (int)cy, ix = (int)cx;   // trunc, curr in [0,223]
    int y0, y1, x0, x1;
    float ty, tx;
    bilin_setup(iy, y0, y1, ty);
    bilin_setup(ix, x0, x1, tx);
    for (int c = tid; c < C_; c += 256) {
        const float* f = curr_f + (size_t)(b * C_ + c) * 196;
        bf[c] = bilin_tap(f, y0, y1, ty, x0, x1, tx);
    }
    __syncthreads();

    // stats over the concatenated token [pre_q | bf | (cy,cx) | first_q]
    float s = 0.f, s2 = 0.f;
    for (int d = tid; d < D_; d += 256) {
        float v;
        if (d < C_)            v = pre_q[(size_t)m * C_ + d];
        else if (d < 2 * C_)   v = bf[d - C_];
        else if (d == 2 * C_)  v = cy;
        else if (d == 2*C_+1)  v = cx;
        else                   v = first_q[(size_t)m * C_ + (d - 2 * C_ - 2)];
        s += v; s2 += v * v;
    }
    block_reduce_2(s, s2, red);
    float mean = s / (float)D_;
    float var = s2 / (float)D_ - mean * mean;
    float inv = rsqrtf(var + EPS_);

    const float negLogDivD = -logf(10000.0f) / (float)D_;
    for (int d = tid; d < D_; d += 256) {
        float v;
        if (d < C_)            v = pre_q[(size_t)m * C_ + d];
        else if (d < 2 * C_)   v = bf[d - C_];
        else if (d == 2 * C_)  v = cy;
        else if (d == 2*C_+1)  v = cx;
        else                   v = first_q[(size_t)m * C_ + (d - 2 * C_ - 2)];
        float ln = ln_g[d] * (v - mean) * inv + ln_b[d];
        int kk = d >> 1;
        float ang = (float)n * expf((float)(2 * kk) * negLogDivD);
        float pe = (d & 1) ? cosf(ang) : sinf(ang);
        tokens[(size_t)m * D_ + d] = ln + pe;
    }
}

// ---------------------------------------------------------------- GEMM
// C[m,o] = sum_k A[m,k]*W[o,k] + bias[o]  (optionally relu). M fixed = 160.
#define GOT 16
#define GKC 32
template <bool RELU>
__global__ __launch_bounds__(256) void gemm_atb(
        const float* __restrict__ A, const float* __restrict__ W,
        const float* __restrict__ bias, float* __restrict__ Cout,
        int K, int O) {
    __shared__ float As[GKC][M_ + 1];   // padded: conflict-free loads
    __shared__ float Ws[GKC][GOT];
    int tid = threadIdx.x;
    int o0 = blockIdx.x * GOT;
    int to = tid & 15;
    int mg = tid >> 4;                  // 0..15, each owns 10 m rows
    float acc[10];
#pragma unroll
    for (int i = 0; i < 10; ++i) acc[i] = 0.f;

    for (int kc = 0; kc < K; kc += GKC) {
#pragma unroll
        for (int j = 0; j < 20; ++j) {          // 160*32/256
            int idx = tid + 256 * j;
            int m = idx >> 5, k = idx & 31;
            int kk = kc + k;
            As[k][m] = (kk < K) ? A[(size_t)m * K + kk] : 0.f;
        }
#pragma unroll
        for (int j = 0; j < 2; ++j) {           // 16*32/256
            int idx = tid + 256 * j;
            int o = idx >> 5, k = idx & 31;
            int oo = o0 + o, kk = kc + k;
            Ws[k][o] = (oo < O && kk < K) ? W[(size_t)oo * K + kk] : 0.f;
        }
        __syncthreads();
#pragma unroll
        for (int k = 0; k < GKC; ++k) {
            float w = Ws[k][to];
#pragma unroll
            for (int i = 0; i < 10; ++i)
                acc[i] += As[k][mg + 16 * i] * w;
        }
        __syncthreads();
    }
    int oo = o0 + to;
    if (oo < O) {
        float bv = bias[oo];
#pragma unroll
        for (int i = 0; i < 10; ++i) {
            float c = acc[i] + bv;
            if (RELU) c = fmaxf(c, 0.f);
            Cout[(size_t)(mg + 16 * i) * O + oo] = c;
        }
    }
}

// ---------------------------------------------------------------- attention
__global__ __launch_bounds__(256) void attn_kernel(const float* __restrict__ qkv,
                                                   float* __restrict__ av) {
    int m = blockIdx.x;       // 0..159 (query row)
    int b = m / N_;
    int tid = threadIdx.x;
    __shared__ float qs[D_];
    __shared__ float sc[N_];

    const float* qrow = qkv + (size_t)m * QKV_;
    for (int d = tid; d < D_; d += 256) qs[d] = qrow[d];
    __syncthreads();

    const float scale = 1.0f / sqrtf((float)D_);
    if (tid < N_) {
        const float* krow = qkv + (size_t)(b * N_ + tid) * QKV_ + D_;
        float s = 0.f;
        for (int d = 0; d < D_; ++d) s += qs[d] * krow[d];
        sc[tid] = s * scale;
    }
    __syncthreads();
    if (tid == 0) {
        float mx = sc[0];
        for (int i = 1; i < N_; ++i) mx = fmaxf(mx, sc[i]);
        float sum = 0.f;
        for (int i = 0; i < N_; ++i) { sc[i] = expf(sc[i] - mx); sum += sc[i]; }
        float rs = 1.0f / sum;
        for (int i = 0; i < N_; ++i) sc[i] *= rs;
    }
    __syncthreads();
    for (int d = tid; d < D_; d += 256) {
        float s = 0.f;
        for (int i = 0; i < N_; ++i)
            s += sc[i] * qkv[(size_t)(b * N_ + i) * QKV_ + 2 * D_ + d];
        av[(size_t)m * D_ + d] = s;
    }
}

// ---------------------------------------------------------------- layernorm
__global__ __launch_bounds__(256) void ln_kernel(const float* __restrict__ xin,
                                                 const float* __restrict__ res,
                                                 const float* __restrict__ g,
                                                 const float* __restrict__ bta,
                                                 float* __restrict__ out) {
    int m = blockIdx.x;
    int tid = threadIdx.x;
    __shared__ float red[10];
    const float* xr = xin + (size_t)m * D_;
    const float* rr = res ? res + (size_t)m * D_ : nullptr;
    float s = 0.f, s2 = 0.f;
    for (int d = tid; d < D_; d += 256) {
        float v = xr[d] + (rr ? rr[d] : 0.f);
        s += v; s2 += v * v;
    }
    block_reduce_2(s, s2, red);
    float mean = s / (float)D_;
    float var = s2 / (float)D_ - mean * mean;
    float inv = rsqrtf(var + EPS_);
    for (int d = tid; d < D_; d += 256) {
        float v = xr[d] + (rr ? rr[d] : 0.f);
        out[(size_t)m * D_ + d] = g[d] * (v - mean) * inv + bta[d];
    }
}

// ---------------------------------------------------------------- update
__global__ __launch_bounds__(256) void update_kernel(const float* __restrict__ outb,
                                                     float* __restrict__ curr,
                                                     float* __restrict__ pre_q,
                                                     float* __restrict__ results) {
    int m = blockIdx.x;
    int tid = threadIdx.x;
    for (int c = tid; c < C_; c += 256)
        pre_q[(size_t)m * C_ + c] += outb[(size_t)m * OD_ + c];
    if (tid < 2) {
        float nc = curr[m * 2 + tid] + outb[(size_t)m * OD_ + C_ + tid];
        nc = fminf(fmaxf(nc, 0.f), 223.f);
        curr[m * 2 + tid] = nc;
        results[m * 2 + tid] = nc;
    }
}

// ---------------------------------------------------------------- launch
extern "C" void kernel_launch(void* const* d_in, const int* in_sizes, int n_in,
                              void* d_out, int out_size, void* d_ws, size_t ws_size,
                              hipStream_t stream) {
    const float* pre_f   = (const float*)d_in[0];
    const float* curr_f  = (const float*)d_in[1];
    const float* first_f = (const float*)d_in[2];
    const int*   prev_b  = (const int*)d_in[3];
    const int*   first_b = (const int*)d_in[4];
    const float* ln_g    = (const float*)d_in[5];
    const float* ln_b    = (const float*)d_in[6];
    const float* ipw     = (const float*)d_in[7];
    const float* ipb     = (const float*)d_in[8];
    const float* opw     = (const float*)d_in[9];
    const float* opb     = (const float*)d_in[10];
    const float* n1g     = (const float*)d_in[11];
    const float* n1b     = (const float*)d_in[12];
    const float* l1w     = (const float*)d_in[13];
    const float* l1b     = (const float*)d_in[14];
    const float* l2w     = (const float*)d_in[15];
    const float* l2b     = (const float*)d_in[16];
    const float* n2g     = (const float*)d_in[17];
    const float* n2b     = (const float*)d_in[18];
    const float* ow      = (const float*)d_in[19];
    const float* ob      = (const float*)d_in[20];
    float* outp = (float*)d_out;

    float* wf = (float*)d_ws;
    size_t off = 0;
    int*   fb_al   = (int*)(wf + off); off += (size_t)B_ * N_ * 2;
    float* curr    = wf + off;         off += (size_t)B_ * N_ * 2;
    float* pre_q   = wf + off;         off += (size_t)M_ * C_;
    float* first_q = wf + off;         off += (size_t)M_ * C_;
    float* tokens  = wf + off;         off += (size_t)M_ * D_;
    float* qkv     = wf + off;         off += (size_t)M_ * QKV_;
    float* av      = wf + off;         off += (size_t)M_ * D_;
    float* aout    = wf + off;         off += (size_t)M_ * D_;
    float* xbuf    = wf + off;         off += (size_t)M_ * D_;
    float* ff1     = wf + off;         off += (size_t)M_ * DFF_;
    float* ffout   = wf + off;         off += (size_t)M_ * D_;
    float* x2      = wf + off;         off += (size_t)M_ * D_;
    float* outb    = wf + off;         off += (size_t)M_ * OD_;
    (void)ws_size; (void)in_sizes; (void)n_in; (void)out_size;

    hipLaunchKernelGGL(align_kernel, dim3(B_), dim3(128), 0, stream,
                       prev_b, first_b, fb_al);
    hipLaunchKernelGGL(gather_init_kernel, dim3(M_), dim3(256), 0, stream,
                       pre_f, first_f, prev_b, fb_al, pre_q, first_q, curr);

    for (int it = 0; it < 3; ++it) {
        hipLaunchKernelGGL(tokens_kernel, dim3(M_), dim3(256), 0, stream,
                           curr_f, pre_q, first_q, curr, ln_g, ln_b, tokens);
        hipLaunchKernelGGL((gemm_atb<false>), dim3((QKV_ + GOT - 1) / GOT), dim3(256), 0, stream,
                           tokens, ipw, ipb, qkv, D_, QKV_);
        hipLaunchKernelGGL(attn_kernel, dim3(M_), dim3(256), 0, stream, qkv, av);
        hipLaunchKernelGGL((gemm_atb<false>), dim3((D_ + GOT - 1) / GOT), dim3(256), 0, stream,
                           av, opw, opb, aout, D_, D_);
        hipLaunchKernelGGL(ln_kernel, dim3(M_), dim3(256), 0, stream,
                           tokens, aout, n1g, n1b, xbuf);
        hipLaunchKernelGGL((gemm_atb<true>), dim3((DFF_ + GOT - 1) / GOT), dim3(256), 0, stream,
                           xbuf, l1w, l1b, ff1, D_, DFF_);
        hipLaunchKernelGGL((gemm_atb<false>), dim3((D_ + GOT - 1) / GOT), dim3(256), 0, stream,
                           ff1, l2w, l2b, ffout, DFF_, D_);
        hipLaunchKernelGGL(ln_kernel, dim3(M_), dim3(256), 0, stream,
                           xbuf, ffout, n2g, n2b, x2);
        hipLaunchKernelGGL((gemm_atb<false>), dim3((OD_ + GOT - 1) / GOT), dim3(256), 0, stream,
                           x2, ow, ob, outb, D_, OD_);
        hipLaunchKernelGGL(update_kernel, dim3(M_), dim3(256), 0, stream,
                           outb, curr, pre_q, outp + (size_t)it * M_ * 2);
    }
}

// Round 3
// 5039.109 us; speedup vs baseline: 1.8779x; 1.8779x over previous
//
#include <hip/hip_runtime.h>
#include <math.h>

#define B_    2
#define C_    1024
#define N_    80
#define D_    3074
#define DFF_  2048
#define OD_   1026      // C+2
#define QKV_  9222      // 3*D
#define M_    160       // B*N token rows
#define EPS_  1e-5f
#define KPD_  3104      // D_ rounded up to multiple of 32 (bf16 activation row stride)

typedef __attribute__((ext_vector_type(8))) short bf16x8;   // 8 bf16 = 4 VGPRs
typedef __attribute__((ext_vector_type(4))) float f32x4;

// fp32 -> bf16 (round-to-nearest-even), bit pattern as short
__device__ inline short f2bf(float f) {
    unsigned u = __float_as_uint(f);
    u += 0x7fffu + ((u >> 16) & 1u);
    return (short)(u >> 16);
}

// ---------------------------------------------------------------- reductions
__device__ inline float wave_sum(float v) {
#pragma unroll
    for (int off = 32; off > 0; off >>= 1) v += __shfl_down(v, off, 64);
    return v;
}

__device__ inline void block_reduce_2(float& s, float& s2, float* red) {
    int tid = threadIdx.x;
    int lane = tid & 63, wid = tid >> 6;
    s = wave_sum(s);
    s2 = wave_sum(s2);
    if (lane == 0) { red[wid] = s; red[4 + wid] = s2; }
    __syncthreads();
    if (tid == 0) {
        red[8] = red[0] + red[1] + red[2] + red[3];
        red[9] = red[4] + red[5] + red[6] + red[7];
    }
    __syncthreads();
    s = red[8]; s2 = red[9];
}

// ---------------------------------------------------------------- bilinear
__device__ inline void bilin_setup(int p, int& i0, int& i1, float& t) {
    float s = (p + 0.5f) * 0.0625f - 0.5f;
    s = fminf(fmaxf(s, 0.0f), 13.0f);
    i0 = (int)s;
    t = s - (float)i0;
    i1 = min(i0 + 1, 13);
}

__device__ inline float bilin_tap(const float* f, int y0, int y1, float ty,
                                  int x0, int x1, float tx) {
    float a = f[y0 * 14 + x0], b = f[y0 * 14 + x1];
    float c = f[y1 * 14 + x0], d = f[y1 * 14 + x1];
    return (1.f - ty) * ((1.f - tx) * a + tx * b) + ty * ((1.f - tx) * c + tx * d);
}

// ---------------------------------------------------------------- K0: align
__global__ __launch_bounds__(128) void align_kernel(const int* __restrict__ prev_b,
                                                    const int* __restrict__ first_b,
                                                    int* __restrict__ fb_al) {
    int b = blockIdx.x;
    int tid = threadIdx.x;
    __shared__ int dist[N_];
    __shared__ int bestIdx;
    if (tid < N_) {
        int s = 0;
        for (int j = 0; j < N_; ++j) {
            int src = (j - tid) % N_;
            if (src < 0) src += N_;
            int dy = prev_b[(b * N_ + j) * 2] - first_b[(b * N_ + src) * 2];
            int dx = prev_b[(b * N_ + j) * 2 + 1] - first_b[(b * N_ + src) * 2 + 1];
            s += abs(dy) + abs(dx);
        }
        dist[tid] = s;
    }
    __syncthreads();
    if (tid == 0) {
        int best = 0, bd = dist[0];
        for (int i = 1; i < N_; ++i)
            if (dist[i] < bd) { bd = dist[i]; best = i; }
        bestIdx = best;
    }
    __syncthreads();
    if (tid < N_) {
        int src = (tid - bestIdx) % N_;
        if (src < 0) src += N_;
        fb_al[(b * N_ + tid) * 2]     = first_b[(b * N_ + src) * 2];
        fb_al[(b * N_ + tid) * 2 + 1] = first_b[(b * N_ + src) * 2 + 1];
    }
}

// -------------------------------------------------- K1: pre_q/first_q gather
__global__ __launch_bounds__(256) void gather_init_kernel(
        const float* __restrict__ pre_f, const float* __restrict__ first_f,
        const int* __restrict__ prev_b, const int* __restrict__ fb_al,
        float* __restrict__ pre_q, float* __restrict__ first_q,
        float* __restrict__ curr) {
    int m = blockIdx.x;
    int b = m / N_;
    int tid = threadIdx.x;
    int py = prev_b[m * 2], px = prev_b[m * 2 + 1];
    int fy = fb_al[m * 2], fx = fb_al[m * 2 + 1];
    int py0, py1, px0, px1, fy0, fy1, fx0, fx1;
    float pty, ptx, fty, ftx;
    bilin_setup(py, py0, py1, pty);
    bilin_setup(px, px0, px1, ptx);
    bilin_setup(fy, fy0, fy1, fty);
    bilin_setup(fx, fx0, fx1, ftx);
    for (int c = tid; c < C_; c += 256) {
        const float* fp = pre_f + (size_t)(b * C_ + c) * 196;
        const float* ff = first_f + (size_t)(b * C_ + c) * 196;
        pre_q[(size_t)m * C_ + c]   = bilin_tap(fp, py0, py1, pty, px0, px1, ptx);
        first_q[(size_t)m * C_ + c] = bilin_tap(ff, fy0, fy1, fty, fx0, fx1, ftx);
    }
    if (tid < 2) curr[m * 2 + tid] = (float)prev_b[m * 2 + tid];
}

// -------------------------------------------------- K2: tokens = LN(cat)+pe
// writes fp32 tokens [M_][D_] (residual) + bf16 padded copy [M_][KPD_]
__global__ __launch_bounds__(256) void tokens_kernel(
        const float* __restrict__ curr_f, const float* __restrict__ pre_q,
        const float* __restrict__ first_q, const float* __restrict__ curr,
        const float* __restrict__ ln_g, const float* __restrict__ ln_b,
        float* __restrict__ tokens, short* __restrict__ tokens_bf) {
    int m = blockIdx.x;
    int b = m / N_;
    int n = m % N_;
    int tid = threadIdx.x;
    __shared__ float bf[C_];
    __shared__ float red[10];

    float cy = curr[m * 2], cx = curr[m * 2 + 1];
    int iy = (int)cy, ix = (int)cx;
    int y0, y1, x0, x1;
    float ty, tx;
    bilin_setup(iy, y0, y1, ty);
    bilin_setup(ix, x0, x1, tx);
    for (int c = tid; c < C_; c += 256) {
        const float* f = curr_f + (size_t)(b * C_ + c) * 196;
        bf[c] = bilin_tap(f, y0, y1, ty, x0, x1, tx);
    }
    __syncthreads();

    float s = 0.f, s2 = 0.f;
    for (int d = tid; d < D_; d += 256) {
        float v;
        if (d < C_)            v = pre_q[(size_t)m * C_ + d];
        else if (d < 2 * C_)   v = bf[d - C_];
        else if (d == 2 * C_)  v = cy;
        else if (d == 2*C_+1)  v = cx;
        else                   v = first_q[(size_t)m * C_ + (d - 2 * C_ - 2)];
        s += v; s2 += v * v;
    }
    block_reduce_2(s, s2, red);
    float mean = s / (float)D_;
    float var = s2 / (float)D_ - mean * mean;
    float inv = rsqrtf(var + EPS_);

    const float negLogDivD = -logf(10000.0f) / (float)D_;
    for (int d = tid; d < KPD_; d += 256) {
        if (d < D_) {
            float v;
            if (d < C_)            v = pre_q[(size_t)m * C_ + d];
            else if (d < 2 * C_)   v = bf[d - C_];
            else if (d == 2 * C_)  v = cy;
            else if (d == 2*C_+1)  v = cx;
            else                   v = first_q[(size_t)m * C_ + (d - 2 * C_ - 2)];
            float ln = ln_g[d] * (v - mean) * inv + ln_b[d];
            int kk = d >> 1;
            float ang = (float)n * expf((float)(2 * kk) * negLogDivD);
            float pe = (d & 1) ? cosf(ang) : sinf(ang);
            float val = ln + pe;
            tokens[(size_t)m * D_ + d] = val;
            tokens_bf[(size_t)m * KPD_ + d] = f2bf(val);
        } else {
            tokens_bf[(size_t)m * KPD_ + d] = 0;
        }
    }
}

// ---------------------------------------------------------------- MFMA GEMM
// C[m,o] = sum_k A[m,k]*W[o,k] + bias[o].  A: bf16 [M_][KpA] zero-padded.
// W: fp32 [O][K], converted to bf16 in-register (each W row is read by exactly
// one wave -> no reuse lost by not pre-converting).
// Block: 256 thr = 4 waves; wave w covers o-strip blockIdx.x*64 + w*16,
// all 10 m-tiles.  No LDS, no barriers: MFMA A/B fragments for 16x16x32 with
// row-major-K operands are direct contiguous 16B loads.
template <bool RELU, bool BF16OUT>
__global__ __launch_bounds__(256) void gemm_mfma(
        const short* __restrict__ A, const float* __restrict__ Wf,
        const float* __restrict__ bias,
        float* __restrict__ Cf, short* __restrict__ Cb,
        int K, int KpA, int O) {
    int lane = threadIdx.x & 63;
    int wave = threadIdx.x >> 6;
    int col  = lane & 15;     // o within strip / A-fragment row
    int quad = lane >> 4;     // k-subrange selector, D-row group
    int o = blockIdx.x * 64 + wave * 16 + col;
    int oc = min(o, O - 1);

    const float* wrow  = Wf + (size_t)oc * K + quad * 8;
    const short* abase = A + (size_t)col * KpA + quad * 8;

    f32x4 acc[10];
#pragma unroll
    for (int t = 0; t < 10; ++t)
#pragma unroll
        for (int r = 0; r < 4; ++r) acc[t][r] = 0.f;

    int Kmain = K & ~31;
    for (int kc = 0; kc < Kmain; kc += 32) {
        // W rows are only 8B-aligned (K=3074 odd*2) -> float2 loads
        float2 w01 = *(const float2*)(wrow + kc);
        float2 w23 = *(const float2*)(wrow + kc + 2);
        float2 w45 = *(const float2*)(wrow + kc + 4);
        float2 w67 = *(const float2*)(wrow + kc + 6);
        bf16x8 bfrag;
        bfrag[0] = f2bf(w01.x); bfrag[1] = f2bf(w01.y);
        bfrag[2] = f2bf(w23.x); bfrag[3] = f2bf(w23.y);
        bfrag[4] = f2bf(w45.x); bfrag[5] = f2bf(w45.y);
        bfrag[6] = f2bf(w67.x); bfrag[7] = f2bf(w67.y);
#pragma unroll
        for (int t = 0; t < 10; ++t) {
            bf16x8 afrag = *(const bf16x8*)(abase + (size_t)t * 16 * KpA + kc);
            acc[t] = __builtin_amdgcn_mfma_f32_16x16x32_bf16(afrag, bfrag, acc[t], 0, 0, 0);
        }
    }
    if (Kmain < K) {   // K tail (D_=3074 -> 2 leftover k); A is zero-padded
        bf16x8 bfrag;
#pragma unroll
        for (int j = 0; j < 8; ++j) {
            int k = Kmain + quad * 8 + j;
            bfrag[j] = (k < K) ? f2bf(Wf[(size_t)oc * K + k]) : (short)0;
        }
#pragma unroll
        for (int t = 0; t < 10; ++t) {
            bf16x8 afrag = *(const bf16x8*)(abase + (size_t)t * 16 * KpA + Kmain);
            acc[t] = __builtin_amdgcn_mfma_f32_16x16x32_bf16(afrag, bfrag, acc[t], 0, 0, 0);
        }
    }
    if (o < O) {
        float bv = bias[o];
#pragma unroll
        for (int t = 0; t < 10; ++t) {
#pragma unroll
            for (int r = 0; r < 4; ++r) {
                int m = t * 16 + quad * 4 + r;   // C/D: col=lane&15, row=quad*4+r
                float c = acc[t][r] + bv;
                if (RELU) c = fmaxf(c, 0.f);
                if (BF16OUT) Cb[(size_t)m * O + o] = f2bf(c);
                else         Cf[(size_t)m * O + o] = c;
            }
        }
    }
}

// ---------------------------------------------------------------- attention
// scores: one wave per (query m, key kk) pair, coalesced dot + shuffle reduce
__global__ __launch_bounds__(256) void scores_kernel(const float* __restrict__ qkv,
                                                     float* __restrict__ sc) {
    int pair = blockIdx.x * 4 + (threadIdx.x >> 6);
    int lane = threadIdx.x & 63;
    int m = pair / N_;
    int kk = pair % N_;
    int b = m / N_;
    const float* q    = qkv + (size_t)m * QKV_;
    const float* krow = qkv + (size_t)(b * N_ + kk) * QKV_ + D_;
    float s = 0.f;
    for (int d = lane; d < D_; d += 64) s += q[d] * krow[d];
    s = wave_sum(s);
    if (lane == 0) sc[m * N_ + kk] = s * (1.0f / sqrtf((float)D_));
}

// softmax (per row) + AV, output bf16 padded [M_][KPD_]
__global__ __launch_bounds__(256) void av_kernel(const float* __restrict__ sc,
                                                 const float* __restrict__ qkv,
                                                 short* __restrict__ av_bf) {
    int m = blockIdx.x;
    int b = m / N_;
    int tid = threadIdx.x;
    __shared__ float p[N_];
    if (tid < N_) p[tid] = sc[m * N_ + tid];
    __syncthreads();
    if (tid == 0) {
        float mx = p[0];
        for (int i = 1; i < N_; ++i) mx = fmaxf(mx, p[i]);
        float sum = 0.f;
        for (int i = 0; i < N_; ++i) { p[i] = expf(p[i] - mx); sum += p[i]; }
        float rs = 1.0f / sum;
        for (int i = 0; i < N_; ++i) p[i] *= rs;
    }
    __syncthreads();
    for (int d = tid; d < KPD_; d += 256) {
        if (d < D_) {
            const float* v = qkv + (size_t)b * N_ * QKV_ + 2 * D_ + d;
            float s = 0.f;
#pragma unroll 8
            for (int k = 0; k < N_; ++k) s += p[k] * v[(size_t)k * QKV_];
            av_bf[(size_t)m * KPD_ + d] = f2bf(s);
        } else {
            av_bf[(size_t)m * KPD_ + d] = 0;
        }
    }
}

// ---------------------------------------------------------------- layernorm
// out = g*(x+res - mean)/sqrt(var+eps)+b ; fp32 out optional, bf16 out padded
template <bool WF32>
__global__ __launch_bounds__(256) void ln_kernel(const float* __restrict__ xin,
                                                 const float* __restrict__ res,
                                                 const float* __restrict__ g,
                                                 const float* __restrict__ bta,
                                                 float* __restrict__ outf,
                                                 short* __restrict__ outb) {
    int m = blockIdx.x;
    int tid = threadIdx.x;
    __shared__ float red[10];
    const float* xr = xin + (size_t)m * D_;
    const float* rr = res + (size_t)m * D_;
    float s = 0.f, s2 = 0.f;
    for (int d = tid; d < D_; d += 256) {
        float v = xr[d] + rr[d];
        s += v; s2 += v * v;
    }
    block_reduce_2(s, s2, red);
    float mean = s / (float)D_;
    float var = s2 / (float)D_ - mean * mean;
    float inv = rsqrtf(var + EPS_);
    for (int d = tid; d < KPD_; d += 256) {
        if (d < D_) {
            float v = xr[d] + rr[d];
            float y = g[d] * (v - mean) * inv + bta[d];
            if (WF32) outf[(size_t)m * D_ + d] = y;
            outb[(size_t)m * KPD_ + d] = f2bf(y);
        } else {
            outb[(size_t)m * KPD_ + d] = 0;
        }
    }
}

// ---------------------------------------------------------------- update
__global__ __launch_bounds__(256) void update_kernel(const float* __restrict__ outb,
                                                     float* __restrict__ curr,
                                                     float* __restrict__ pre_q,
                                                     float* __restrict__ results) {
    int m = blockIdx.x;
    int tid = threadIdx.x;
    for (int c = tid; c < C_; c += 256)
        pre_q[(size_t)m * C_ + c] += outb[(size_t)m * OD_ + c];
    if (tid < 2) {
        float nc = curr[m * 2 + tid] + outb[(size_t)m * OD_ + C_ + tid];
        nc = fminf(fmaxf(nc, 0.f), 223.f);
        curr[m * 2 + tid] = nc;
        results[m * 2 + tid] = nc;
    }
}

// ---------------------------------------------------------------- launch
extern "C" void kernel_launch(void* const* d_in, const int* in_sizes, int n_in,
                              void* d_out, int out_size, void* d_ws, size_t ws_size,
                              hipStream_t stream) {
    const float* pre_f   = (const float*)d_in[0];
    const float* curr_f  = (const float*)d_in[1];
    const float* first_f = (const float*)d_in[2];
    const int*   prev_b  = (const int*)d_in[3];
    const int*   first_b = (const int*)d_in[4];
    const float* ln_g    = (const float*)d_in[5];
    const float* ln_b    = (const float*)d_in[6];
    const float* ipw     = (const float*)d_in[7];
    const float* ipb     = (const float*)d_in[8];
    const float* opw     = (const float*)d_in[9];
    const float* opb     = (const float*)d_in[10];
    const float* n1g     = (const float*)d_in[11];
    const float* n1b     = (const float*)d_in[12];
    const float* l1w     = (const float*)d_in[13];
    const float* l1b     = (const float*)d_in[14];
    const float* l2w     = (const float*)d_in[15];
    const float* l2b     = (const float*)d_in[16];
    const float* n2g     = (const float*)d_in[17];
    const float* n2b     = (const float*)d_in[18];
    const float* ow      = (const float*)d_in[19];
    const float* ob      = (const float*)d_in[20];
    float* outp = (float*)d_out;

    float* wf = (float*)d_ws;
    size_t off = 0;
    int*   fb_al   = (int*)(wf + off); off += 320;
    float* curr    = wf + off;         off += 320;
    float* pre_q   = wf + off;         off += (size_t)M_ * C_;
    float* first_q = wf + off;         off += (size_t)M_ * C_;
    float* tokens  = wf + off;         off += (size_t)M_ * D_;
    float* qkv     = wf + off;         off += (size_t)M_ * QKV_;
    float* aout    = wf + off;         off += (size_t)M_ * D_;
    float* xbuf    = wf + off;         off += (size_t)M_ * D_;
    float* ffout   = wf + off;         off += (size_t)M_ * D_;
    float* outb    = wf + off;         off += (size_t)M_ * OD_;
    float* sc      = wf + off;         off += (size_t)M_ * N_;
    short* tokens_bf = (short*)(wf + off); off += (size_t)M_ * KPD_ / 2;
    short* x_bf      = (short*)(wf + off); off += (size_t)M_ * KPD_ / 2;
    short* x2_bf     = (short*)(wf + off); off += (size_t)M_ * KPD_ / 2;
    short* av_bf     = (short*)(wf + off); off += (size_t)M_ * KPD_ / 2;
    short* ff1_bf    = (short*)(wf + off); off += (size_t)M_ * DFF_ / 2;
    (void)ws_size; (void)in_sizes; (void)n_in; (void)out_size;

    hipLaunchKernelGGL(align_kernel, dim3(B_), dim3(128), 0, stream,
                       prev_b, first_b, fb_al);
    hipLaunchKernelGGL(gather_init_kernel, dim3(M_), dim3(256), 0, stream,
                       pre_f, first_f, prev_b, fb_al, pre_q, first_q, curr);

    for (int it = 0; it < 3; ++it) {
        hipLaunchKernelGGL(tokens_kernel, dim3(M_), dim3(256), 0, stream,
                           curr_f, pre_q, first_q, curr, ln_g, ln_b, tokens, tokens_bf);
        hipLaunchKernelGGL((gemm_mfma<false, false>), dim3(145), dim3(256), 0, stream,
                           tokens_bf, ipw, ipb, qkv, (short*)nullptr, D_, KPD_, QKV_);
        hipLaunchKernelGGL(scores_kernel, dim3(3200), dim3(256), 0, stream, qkv, sc);
        hipLaunchKernelGGL(av_kernel, dim3(M_), dim3(256), 0, stream, sc, qkv, av_bf);
        hipLaunchKernelGGL((gemm_mfma<false, false>), dim3(49), dim3(256), 0, stream,
                           av_bf, opw, opb, aout, (short*)nullptr, D_, KPD_, D_);
        hipLaunchKernelGGL((ln_kernel<true>), dim3(M_), dim3(256), 0, stream,
                           tokens, aout, n1g, n1b, xbuf, x_bf);
        hipLaunchKernelGGL((gemm_mfma<true, true>), dim3(32), dim3(256), 0, stream,
                           x_bf, l1w, l1b, (float*)nullptr, ff1_bf, D_, KPD_, DFF_);
        hipLaunchKernelGGL((gemm_mfma<false, false>), dim3(49), dim3(256), 0, stream,
                           ff1_bf, l2w, l2b, ffout, (short*)nullptr, DFF_, DFF_, D_);
        hipLaunchKernelGGL((ln_kernel<false>), dim3(M_), dim3(256), 0, stream,
                           xbuf, ffout, n2g, n2b, (float*)nullptr, x2_bf);
        hipLaunchKernelGGL((gemm_mfma<false, false>), dim3(17), dim3(256), 0, stream,
                           x2_bf, ow, ob, outb, (short*)nullptr, D_, KPD_, OD_);
        hipLaunchKernelGGL(update_kernel, dim3(M_), dim3(256), 0, stream,
                           outb, curr, pre_q, outp + (size_t)it * M_ * 2);
    }
}

// Round 4
// 1520.252 us; speedup vs baseline: 6.2246x; 3.3147x over previous
//
#include <hip/hip_runtime.h>
#include <math.h>

#define B_    2
#define C_    1024
#define N_    80
#define D_    3074
#define DFF_  2048
#define OD_   1026      // C+2
#define QKV_  9222      // 3*D
#define M_    160       // B*N token rows
#define EPS_  1e-5f
#define KPD_  3104      // D_ rounded up to multiple of 32 (bf16 activation row stride)

typedef __attribute__((ext_vector_type(8))) short bf16x8;   // 8 bf16 = 4 VGPRs
typedef __attribute__((ext_vector_type(4))) float f32x4;

// fp32 -> bf16 (round-to-nearest-even), bit pattern as short
__device__ inline short f2bf(float f) {
    unsigned u = __float_as_uint(f);
    u += 0x7fffu + ((u >> 16) & 1u);
    return (short)(u >> 16);
}

// ---------------------------------------------------------------- reductions
__device__ inline float wave_sum(float v) {
#pragma unroll
    for (int off = 32; off > 0; off >>= 1) v += __shfl_down(v, off, 64);
    return v;
}

__device__ inline void block_reduce_2(float& s, float& s2, float* red) {
    int tid = threadIdx.x;
    int lane = tid & 63, wid = tid >> 6;
    s = wave_sum(s);
    s2 = wave_sum(s2);
    if (lane == 0) { red[wid] = s; red[4 + wid] = s2; }
    __syncthreads();
    if (tid == 0) {
        red[8] = red[0] + red[1] + red[2] + red[3];
        red[9] = red[4] + red[5] + red[6] + red[7];
    }
    __syncthreads();
    s = red[8]; s2 = red[9];
}

// ---------------------------------------------------------------- bilinear
__device__ inline void bilin_setup(int p, int& i0, int& i1, float& t) {
    float s = (p + 0.5f) * 0.0625f - 0.5f;
    s = fminf(fmaxf(s, 0.0f), 13.0f);
    i0 = (int)s;
    t = s - (float)i0;
    i1 = min(i0 + 1, 13);
}

__device__ inline float bilin_tap(const float* f, int y0, int y1, float ty,
                                  int x0, int x1, float tx) {
    float a = f[y0 * 14 + x0], b = f[y0 * 14 + x1];
    float c = f[y1 * 14 + x0], d = f[y1 * 14 + x1];
    return (1.f - ty) * ((1.f - tx) * a + tx * b) + ty * ((1.f - tx) * c + tx * d);
}

// ---------------------------------------------------------------- K0: align
__global__ __launch_bounds__(128) void align_kernel(const int* __restrict__ prev_b,
                                                    const int* __restrict__ first_b,
                                                    int* __restrict__ fb_al) {
    int b = blockIdx.x;
    int tid = threadIdx.x;
    __shared__ int dist[N_];
    __shared__ int bestIdx;
    if (tid < N_) {
        int s = 0;
        for (int j = 0; j < N_; ++j) {
            int src = (j - tid) % N_;
            if (src < 0) src += N_;
            int dy = prev_b[(b * N_ + j) * 2] - first_b[(b * N_ + src) * 2];
            int dx = prev_b[(b * N_ + j) * 2 + 1] - first_b[(b * N_ + src) * 2 + 1];
            s += abs(dy) + abs(dx);
        }
        dist[tid] = s;
    }
    __syncthreads();
    if (tid == 0) {
        int best = 0, bd = dist[0];
        for (int i = 1; i < N_; ++i)
            if (dist[i] < bd) { bd = dist[i]; best = i; }
        bestIdx = best;
    }
    __syncthreads();
    if (tid < N_) {
        int src = (tid - bestIdx) % N_;
        if (src < 0) src += N_;
        fb_al[(b * N_ + tid) * 2]     = first_b[(b * N_ + src) * 2];
        fb_al[(b * N_ + tid) * 2 + 1] = first_b[(b * N_ + src) * 2 + 1];
    }
}

// -------------------------------------------------- K1: pre_q/first_q gather
__global__ __launch_bounds__(256) void gather_init_kernel(
        const float* __restrict__ pre_f, const float* __restrict__ first_f,
        const int* __restrict__ prev_b, const int* __restrict__ fb_al,
        float* __restrict__ pre_q, float* __restrict__ first_q,
        float* __restrict__ curr) {
    int m = blockIdx.x;
    int b = m / N_;
    int tid = threadIdx.x;
    int py = prev_b[m * 2], px = prev_b[m * 2 + 1];
    int fy = fb_al[m * 2], fx = fb_al[m * 2 + 1];
    int py0, py1, px0, px1, fy0, fy1, fx0, fx1;
    float pty, ptx, fty, ftx;
    bilin_setup(py, py0, py1, pty);
    bilin_setup(px, px0, px1, ptx);
    bilin_setup(fy, fy0, fy1, fty);
    bilin_setup(fx, fx0, fx1, ftx);
    for (int c = tid; c < C_; c += 256) {
        const float* fp = pre_f + (size_t)(b * C_ + c) * 196;
        const float* ff = first_f + (size_t)(b * C_ + c) * 196;
        pre_q[(size_t)m * C_ + c]   = bilin_tap(fp, py0, py1, pty, px0, px1, ptx);
        first_q[(size_t)m * C_ + c] = bilin_tap(ff, fy0, fy1, fty, fx0, fx1, ftx);
    }
    if (tid < 2) curr[m * 2 + tid] = (float)prev_b[m * 2 + tid];
}

// -------------------------------------------------- K2: tokens = LN(cat)+pe
__global__ __launch_bounds__(256) void tokens_kernel(
        const float* __restrict__ curr_f, const float* __restrict__ pre_q,
        const float* __restrict__ first_q, const float* __restrict__ curr,
        const float* __restrict__ ln_g, const float* __restrict__ ln_b,
        float* __restrict__ tokens, short* __restrict__ tokens_bf) {
    int m = blockIdx.x;
    int b = m / N_;
    int n = m % N_;
    int tid = threadIdx.x;
    __shared__ float bf[C_];
    __shared__ float red[10];

    float cy = curr[m * 2], cx = curr[m * 2 + 1];
    int iy = (int)cy, ix = (int)cx;
    int y0, y1, x0, x1;
    float ty, tx;
    bilin_setup(iy, y0, y1, ty);
    bilin_setup(ix, x0, x1, tx);
    for (int c = tid; c < C_; c += 256) {
        const float* f = curr_f + (size_t)(b * C_ + c) * 196;
        bf[c] = bilin_tap(f, y0, y1, ty, x0, x1, tx);
    }
    __syncthreads();

    float s = 0.f, s2 = 0.f;
    for (int d = tid; d < D_; d += 256) {
        float v;
        if (d < C_)            v = pre_q[(size_t)m * C_ + d];
        else if (d < 2 * C_)   v = bf[d - C_];
        else if (d == 2 * C_)  v = cy;
        else if (d == 2*C_+1)  v = cx;
        else                   v = first_q[(size_t)m * C_ + (d - 2 * C_ - 2)];
        s += v; s2 += v * v;
    }
    block_reduce_2(s, s2, red);
    float mean = s / (float)D_;
    float var = s2 / (float)D_ - mean * mean;
    float inv = rsqrtf(var + EPS_);

    const float negLogDivD = -logf(10000.0f) / (float)D_;
    for (int d = tid; d < KPD_; d += 256) {
        if (d < D_) {
            float v;
            if (d < C_)            v = pre_q[(size_t)m * C_ + d];
            else if (d < 2 * C_)   v = bf[d - C_];
            else if (d == 2 * C_)  v = cy;
            else if (d == 2*C_+1)  v = cx;
            else                   v = first_q[(size_t)m * C_ + (d - 2 * C_ - 2)];
            float ln = ln_g[d] * (v - mean) * inv + ln_b[d];
            int kk = d >> 1;
            float ang = (float)n * expf((float)(2 * kk) * negLogDivD);
            float pe = (d & 1) ? cosf(ang) : sinf(ang);
            float val = ln + pe;
            tokens[(size_t)m * D_ + d] = val;
            tokens_bf[(size_t)m * KPD_ + d] = f2bf(val);
        } else {
            tokens_bf[(size_t)m * KPD_ + d] = 0;
        }
    }
}

// ------------------------------------------------ MFMA GEMM with split-K
// C[m,o] (+)= sum_{k in chunk} A[m,k]*W[o,k]  via fp32 atomicAdd.
// grid = (ceil(O/64), S); chunk = [blockIdx.y*KC, min(K, +KC)). Bias from
// split 0 only. Output must be zeroed before launch. A: bf16 [M_][KpA]
// zero-padded. W: fp32 [O][K], converted to bf16 in-register (each W row
// read by exactly one wave -> no reuse lost). No LDS, no barriers.
__global__ __launch_bounds__(256) void gemm_mfma_sk(
        const short* __restrict__ A, const float* __restrict__ Wf,
        const float* __restrict__ bias, float* __restrict__ Cout,
        int K, int KpA, int O, int KC) {
    int kc0 = blockIdx.y * KC;
    if (kc0 >= K) return;                 // empty chunk (ragged split)
    int kend = min(K, kc0 + KC);

    int lane = threadIdx.x & 63;
    int wave = threadIdx.x >> 6;
    int col  = lane & 15;     // o within strip / A-fragment row
    int quad = lane >> 4;     // k-subrange selector, D-row group
    int o = blockIdx.x * 64 + wave * 16 + col;
    int oc = min(o, O - 1);

    const float* wrow  = Wf + (size_t)oc * K + quad * 8;
    const short* abase = A + (size_t)col * KpA + quad * 8;

    f32x4 acc[10];
#pragma unroll
    for (int t = 0; t < 10; ++t)
#pragma unroll
        for (int r = 0; r < 4; ++r) acc[t][r] = 0.f;

    int kmain = kc0 + ((kend - kc0) & ~31);
    for (int kc = kc0; kc < kmain; kc += 32) {
        // W rows are only 8B-aligned (K=3074) -> float2 loads
        float2 w01 = *(const float2*)(wrow + kc);
        float2 w23 = *(const float2*)(wrow + kc + 2);
        float2 w45 = *(const float2*)(wrow + kc + 4);
        float2 w67 = *(const float2*)(wrow + kc + 6);
        bf16x8 bfrag;
        bfrag[0] = f2bf(w01.x); bfrag[1] = f2bf(w01.y);
        bfrag[2] = f2bf(w23.x); bfrag[3] = f2bf(w23.y);
        bfrag[4] = f2bf(w45.x); bfrag[5] = f2bf(w45.y);
        bfrag[6] = f2bf(w67.x); bfrag[7] = f2bf(w67.y);
#pragma unroll
        for (int t = 0; t < 10; ++t) {
            bf16x8 afrag = *(const bf16x8*)(abase + (size_t)t * 16 * KpA + kc);
            acc[t] = __builtin_amdgcn_mfma_f32_16x16x32_bf16(afrag, bfrag, acc[t], 0, 0, 0);
        }
    }
    if (kmain < kend) {   // ragged tail (only in last non-empty chunk); A zero-padded
        bf16x8 bfrag;
#pragma unroll
        for (int j = 0; j < 8; ++j) {
            int k = kmain + quad * 8 + j;
            bfrag[j] = (k < kend) ? f2bf(Wf[(size_t)oc * K + k]) : (short)0;
        }
#pragma unroll
        for (int t = 0; t < 10; ++t) {
            bf16x8 afrag = *(const bf16x8*)(abase + (size_t)t * 16 * KpA + kmain);
            acc[t] = __builtin_amdgcn_mfma_f32_16x16x32_bf16(afrag, bfrag, acc[t], 0, 0, 0);
        }
    }
    if (o < O) {
        float bv = (blockIdx.y == 0) ? bias[o] : 0.f;
#pragma unroll
        for (int t = 0; t < 10; ++t) {
#pragma unroll
            for (int r = 0; r < 4; ++r) {
                int m = t * 16 + quad * 4 + r;   // C/D: col=lane&15, row=quad*4+r
                atomicAdd(&Cout[(size_t)m * O + o], acc[t][r] + bv);
            }
        }
    }
}

// ------------------------------------------------ relu + bf16 convert (ff1)
__global__ __launch_bounds__(256) void relu_cvt_kernel(const float* __restrict__ in,
                                                       short* __restrict__ out,
                                                       int n) {
    int i = blockIdx.x * 256 + threadIdx.x;
    if (i < n) out[i] = f2bf(fmaxf(in[i], 0.f));
}

// ---------------------------------------------------------------- attention
__global__ __launch_bounds__(256) void scores_kernel(const float* __restrict__ qkv,
                                                     float* __restrict__ sc) {
    int pair = blockIdx.x * 4 + (threadIdx.x >> 6);
    int lane = threadIdx.x & 63;
    int m = pair / N_;
    int kk = pair % N_;
    int b = m / N_;
    const float* q    = qkv + (size_t)m * QKV_;
    const float* krow = qkv + (size_t)(b * N_ + kk) * QKV_ + D_;
    float s = 0.f;
    for (int d = lane; d < D_; d += 64) s += q[d] * krow[d];
    s = wave_sum(s);
    if (lane == 0) sc[m * N_ + kk] = s * (1.0f / sqrtf((float)D_));
}

__global__ __launch_bounds__(256) void av_kernel(const float* __restrict__ sc,
                                                 const float* __restrict__ qkv,
                                                 short* __restrict__ av_bf) {
    int m = blockIdx.x;
    int b = m / N_;
    int tid = threadIdx.x;
    __shared__ float p[N_];
    if (tid < N_) p[tid] = sc[m * N_ + tid];
    __syncthreads();
    if (tid == 0) {
        float mx = p[0];
        for (int i = 1; i < N_; ++i) mx = fmaxf(mx, p[i]);
        float sum = 0.f;
        for (int i = 0; i < N_; ++i) { p[i] = expf(p[i] - mx); sum += p[i]; }
        float rs = 1.0f / sum;
        for (int i = 0; i < N_; ++i) p[i] *= rs;
    }
    __syncthreads();
    for (int d = tid; d < KPD_; d += 256) {
        if (d < D_) {
            const float* v = qkv + (size_t)b * N_ * QKV_ + 2 * D_ + d;
            float s = 0.f;
#pragma unroll 8
            for (int k = 0; k < N_; ++k) s += p[k] * v[(size_t)k * QKV_];
            av_bf[(size_t)m * KPD_ + d] = f2bf(s);
        } else {
            av_bf[(size_t)m * KPD_ + d] = 0;
        }
    }
}

// ---------------------------------------------------------------- layernorm
template <bool WF32>
__global__ __launch_bounds__(256) void ln_kernel(const float* __restrict__ xin,
                                                 const float* __restrict__ res,
                                                 const float* __restrict__ g,
                                                 const float* __restrict__ bta,
                                                 float* __restrict__ outf,
                                                 short* __restrict__ outb) {
    int m = blockIdx.x;
    int tid = threadIdx.x;
    __shared__ float red[10];
    const float* xr = xin + (size_t)m * D_;
    const float* rr = res + (size_t)m * D_;
    float s = 0.f, s2 = 0.f;
    for (int d = tid; d < D_; d += 256) {
        float v = xr[d] + rr[d];
        s += v; s2 += v * v;
    }
    block_reduce_2(s, s2, red);
    float mean = s / (float)D_;
    float var = s2 / (float)D_ - mean * mean;
    float inv = rsqrtf(var + EPS_);
    for (int d = tid; d < KPD_; d += 256) {
        if (d < D_) {
            float v = xr[d] + rr[d];
            float y = g[d] * (v - mean) * inv + bta[d];
            if (WF32) outf[(size_t)m * D_ + d] = y;
            outb[(size_t)m * KPD_ + d] = f2bf(y);
        } else {
            outb[(size_t)m * KPD_ + d] = 0;
        }
    }
}

// ---------------------------------------------------------------- update
__global__ __launch_bounds__(256) void update_kernel(const float* __restrict__ outb,
                                                     float* __restrict__ curr,
                                                     float* __restrict__ pre_q,
                                                     float* __restrict__ results) {
    int m = blockIdx.x;
    int tid = threadIdx.x;
    for (int c = tid; c < C_; c += 256)
        pre_q[(size_t)m * C_ + c] += outb[(size_t)m * OD_ + c];
    if (tid < 2) {
        float nc = curr[m * 2 + tid] + outb[(size_t)m * OD_ + C_ + tid];
        nc = fminf(fmaxf(nc, 0.f), 223.f);
        curr[m * 2 + tid] = nc;
        results[m * 2 + tid] = nc;
    }
}

// ---------------------------------------------------------------- launch
extern "C" void kernel_launch(void* const* d_in, const int* in_sizes, int n_in,
                              void* d_out, int out_size, void* d_ws, size_t ws_size,
                              hipStream_t stream) {
    const float* pre_f   = (const float*)d_in[0];
    const float* curr_f  = (const float*)d_in[1];
    const float* first_f = (const float*)d_in[2];
    const int*   prev_b  = (const int*)d_in[3];
    const int*   first_b = (const int*)d_in[4];
    const float* ln_g    = (const float*)d_in[5];
    const float* ln_b    = (const float*)d_in[6];
    const float* ipw     = (const float*)d_in[7];
    const float* ipb     = (const float*)d_in[8];
    const float* opw     = (const float*)d_in[9];
    const float* opb     = (const float*)d_in[10];
    const float* n1g     = (const float*)d_in[11];
    const float* n1b     = (const float*)d_in[12];
    const float* l1w     = (const float*)d_in[13];
    const float* l1b     = (const float*)d_in[14];
    const float* l2w     = (const float*)d_in[15];
    const float* l2b     = (const float*)d_in[16];
    const float* n2g     = (const float*)d_in[17];
    const float* n2b     = (const float*)d_in[18];
    const float* ow      = (const float*)d_in[19];
    const float* ob      = (const float*)d_in[20];
    float* outp = (float*)d_out;

    float* wf = (float*)d_ws;
    size_t off = 0;
    int*   fb_al   = (int*)(wf + off); off += 320;
    float* curr    = wf + off;         off += 320;
    float* pre_q   = wf + off;         off += (size_t)M_ * C_;
    float* first_q = wf + off;         off += (size_t)M_ * C_;
    float* tokens  = wf + off;         off += (size_t)M_ * D_;
    float* qkv     = wf + off;         off += (size_t)M_ * QKV_;
    float* aout    = wf + off;         off += (size_t)M_ * D_;
    float* xbuf    = wf + off;         off += (size_t)M_ * D_;
    float* ff1f    = wf + off;         off += (size_t)M_ * DFF_;
    float* ffout   = wf + off;         off += (size_t)M_ * D_;
    float* outb    = wf + off;         off += (size_t)M_ * OD_;
    float* sc      = wf + off;         off += (size_t)M_ * N_;
    short* tokens_bf = (short*)(wf + off); off += (size_t)M_ * KPD_ / 2;
    short* x_bf      = (short*)(wf + off); off += (size_t)M_ * KPD_ / 2;
    short* x2_bf     = (short*)(wf + off); off += (size_t)M_ * KPD_ / 2;
    short* av_bf     = (short*)(wf + off); off += (size_t)M_ * KPD_ / 2;
    short* ff1_bf    = (short*)(wf + off); off += (size_t)M_ * DFF_ / 2;
    (void)ws_size; (void)in_sizes; (void)n_in; (void)out_size;

    hipLaunchKernelGGL(align_kernel, dim3(B_), dim3(128), 0, stream,
                       prev_b, first_b, fb_al);
    hipLaunchKernelGGL(gather_init_kernel, dim3(M_), dim3(256), 0, stream,
                       pre_f, first_f, prev_b, fb_al, pre_q, first_q, curr);

    for (int it = 0; it < 3; ++it) {
        // zero split-K accumulation buffers for this iteration
        hipMemsetAsync(qkv,   0, (size_t)M_ * QKV_ * 4, stream);
        hipMemsetAsync(aout,  0, (size_t)M_ * D_   * 4, stream);
        hipMemsetAsync(ff1f,  0, (size_t)M_ * DFF_ * 4, stream);
        hipMemsetAsync(ffout, 0, (size_t)M_ * D_   * 4, stream);
        hipMemsetAsync(outb,  0, (size_t)M_ * OD_  * 4, stream);

        hipLaunchKernelGGL(tokens_kernel, dim3(M_), dim3(256), 0, stream,
                           curr_f, pre_q, first_q, curr, ln_g, ln_b, tokens, tokens_bf);
        // qkv: O=9222, S=4, KC=800 -> 580 blocks
        hipLaunchKernelGGL(gemm_mfma_sk, dim3(145, 4), dim3(256), 0, stream,
                           tokens_bf, ipw, ipb, qkv, D_, KPD_, QKV_, 800);
        hipLaunchKernelGGL(scores_kernel, dim3(3200), dim3(256), 0, stream, qkv, sc);
        hipLaunchKernelGGL(av_kernel, dim3(M_), dim3(256), 0, stream, sc, qkv, av_bf);
        // out-proj: O=3074, S=8, KC=416 -> 392 blocks
        hipLaunchKernelGGL(gemm_mfma_sk, dim3(49, 8), dim3(256), 0, stream,
                           av_bf, opw, opb, aout, D_, KPD_, D_, 416);
        hipLaunchKernelGGL((ln_kernel<true>), dim3(M_), dim3(256), 0, stream,
                           tokens, aout, n1g, n1b, xbuf, x_bf);
        // ff1: O=2048, S=16, KC=224 -> 512 blocks (2 empty splits early-exit)
        hipLaunchKernelGGL(gemm_mfma_sk, dim3(32, 16), dim3(256), 0, stream,
                           x_bf, l1w, l1b, ff1f, D_, KPD_, DFF_, 224);
        hipLaunchKernelGGL(relu_cvt_kernel, dim3((M_ * DFF_ + 255) / 256), dim3(256), 0, stream,
                           ff1f, ff1_bf, M_ * DFF_);
        // ff2: K=2048, O=3074, S=8, KC=256 -> 392 blocks
        hipLaunchKernelGGL(gemm_mfma_sk, dim3(49, 8), dim3(256), 0, stream,
                           ff1_bf, l2w, l2b, ffout, DFF_, DFF_, D_, 256);
        hipLaunchKernelGGL((ln_kernel<false>), dim3(M_), dim3(256), 0, stream,
                           xbuf, ffout, n2g, n2b, (float*)nullptr, x2_bf);
        // head: O=1026, S=24, KC=160 -> 408 blocks (4 empty splits early-exit)
        hipLaunchKernelGGL(gemm_mfma_sk, dim3(17, 24), dim3(256), 0, stream,
                           x2_bf, ow, ob, outb, D_, KPD_, OD_, 160);
        hipLaunchKernelGGL(update_kernel, dim3(M_), dim3(256), 0, stream,
                           outb, curr, pre_q, outp + (size_t)it * M_ * 2);
    }
}

// Round 5
// 1159.210 us; speedup vs baseline: 8.1633x; 1.3115x over previous
//
#include <hip/hip_runtime.h>
#include <math.h>

#define B_    2
#define C_    1024
#define N_    80
#define D_    3074
#define DFF_  2048
#define OD_   1026      // C+2
#define QKV_  9222      // 3*D
#define M_    160       // B*N token rows
#define EPS_  1e-5f
#define KPD_  3104      // D_ rounded up to multiple of 32 (bf16 row stride)

typedef __attribute__((ext_vector_type(8))) short bf16x8;   // 8 bf16 = 4 VGPRs
typedef __attribute__((ext_vector_type(4))) float f32x4;

// fp32 -> bf16 (round-to-nearest-even), bit pattern as short
__device__ inline short f2bf(float f) {
    unsigned u = __float_as_uint(f);
    u += 0x7fffu + ((u >> 16) & 1u);
    return (short)(u >> 16);
}

// ---------------------------------------------------------------- reductions
__device__ inline float wave_sum(float v) {
#pragma unroll
    for (int off = 32; off > 0; off >>= 1) v += __shfl_down(v, off, 64);
    return v;
}

__device__ inline float wave_max(float v) {
#pragma unroll
    for (int off = 32; off > 0; off >>= 1) v = fmaxf(v, __shfl_down(v, off, 64));
    return v;
}

__device__ inline void block_reduce_2(float& s, float& s2, float* red) {
    int tid = threadIdx.x;
    int lane = tid & 63, wid = tid >> 6;
    s = wave_sum(s);
    s2 = wave_sum(s2);
    if (lane == 0) { red[wid] = s; red[4 + wid] = s2; }
    __syncthreads();
    if (tid == 0) {
        red[8] = red[0] + red[1] + red[2] + red[3];
        red[9] = red[4] + red[5] + red[6] + red[7];
    }
    __syncthreads();
    s = red[8]; s2 = red[9];
}

// ---------------------------------------------------------------- bilinear
__device__ inline void bilin_setup(int p, int& i0, int& i1, float& t) {
    float s = (p + 0.5f) * 0.0625f - 0.5f;
    s = fminf(fmaxf(s, 0.0f), 13.0f);
    i0 = (int)s;
    t = s - (float)i0;
    i1 = min(i0 + 1, 13);
}

__device__ inline float bilin_tap(const float* f, int y0, int y1, float ty,
                                  int x0, int x1, float tx) {
    float a = f[y0 * 14 + x0], b = f[y0 * 14 + x1];
    float c = f[y1 * 14 + x0], d = f[y1 * 14 + x1];
    return (1.f - ty) * ((1.f - tx) * a + tx * b) + ty * ((1.f - tx) * c + tx * d);
}

// ---------------------------------------------------------------- K0: align
__global__ __launch_bounds__(128) void align_kernel(const int* __restrict__ prev_b,
                                                    const int* __restrict__ first_b,
                                                    int* __restrict__ fb_al) {
    int b = blockIdx.x;
    int tid = threadIdx.x;
    __shared__ int dist[N_];
    __shared__ int bestIdx;
    if (tid < N_) {
        int s = 0;
        for (int j = 0; j < N_; ++j) {
            int src = (j - tid) % N_;
            if (src < 0) src += N_;
            int dy = prev_b[(b * N_ + j) * 2] - first_b[(b * N_ + src) * 2];
            int dx = prev_b[(b * N_ + j) * 2 + 1] - first_b[(b * N_ + src) * 2 + 1];
            s += abs(dy) + abs(dx);
        }
        dist[tid] = s;
    }
    __syncthreads();
    if (tid == 0) {
        int best = 0, bd = dist[0];
        for (int i = 1; i < N_; ++i)
            if (dist[i] < bd) { bd = dist[i]; best = i; }
        bestIdx = best;
    }
    __syncthreads();
    if (tid < N_) {
        int src = (tid - bestIdx) % N_;
        if (src < 0) src += N_;
        fb_al[(b * N_ + tid) * 2]     = first_b[(b * N_ + src) * 2];
        fb_al[(b * N_ + tid) * 2 + 1] = first_b[(b * N_ + src) * 2 + 1];
    }
}

// -------------------------------------------------- K1: pre_q/first_q gather
__global__ __launch_bounds__(256) void gather_init_kernel(
        const float* __restrict__ pre_f, const float* __restrict__ first_f,
        const int* __restrict__ prev_b, const int* __restrict__ fb_al,
        float* __restrict__ pre_q, float* __restrict__ first_q,
        float* __restrict__ curr) {
    int m = blockIdx.x;
    int b = m / N_;
    int tid = threadIdx.x;
    int py = prev_b[m * 2], px = prev_b[m * 2 + 1];
    int fy = fb_al[m * 2], fx = fb_al[m * 2 + 1];
    int py0, py1, px0, px1, fy0, fy1, fx0, fx1;
    float pty, ptx, fty, ftx;
    bilin_setup(py, py0, py1, pty);
    bilin_setup(px, px0, px1, ptx);
    bilin_setup(fy, fy0, fy1, fty);
    bilin_setup(fx, fx0, fx1, ftx);
    for (int c = tid; c < C_; c += 256) {
        const float* fp = pre_f + (size_t)(b * C_ + c) * 196;
        const float* ff = first_f + (size_t)(b * C_ + c) * 196;
        pre_q[(size_t)m * C_ + c]   = bilin_tap(fp, py0, py1, pty, px0, px1, ptx);
        first_q[(size_t)m * C_ + c] = bilin_tap(ff, fy0, fy1, fty, fx0, fx1, ftx);
    }
    if (tid < 2) curr[m * 2 + tid] = (float)prev_b[m * 2 + tid];
}

// -------------------------------------------------- K2: tokens = LN(cat)+pe
__global__ __launch_bounds__(256) void tokens_kernel(
        const float* __restrict__ curr_f, const float* __restrict__ pre_q,
        const float* __restrict__ first_q, const float* __restrict__ curr,
        const float* __restrict__ ln_g, const float* __restrict__ ln_b,
        float* __restrict__ tokens, short* __restrict__ tokens_bf) {
    int m = blockIdx.x;
    int b = m / N_;
    int n = m % N_;
    int tid = threadIdx.x;
    __shared__ float bf[C_];
    __shared__ float red[10];

    float cy = curr[m * 2], cx = curr[m * 2 + 1];
    int iy = (int)cy, ix = (int)cx;
    int y0, y1, x0, x1;
    float ty, tx;
    bilin_setup(iy, y0, y1, ty);
    bilin_setup(ix, x0, x1, tx);
    for (int c = tid; c < C_; c += 256) {
        const float* f = curr_f + (size_t)(b * C_ + c) * 196;
        bf[c] = bilin_tap(f, y0, y1, ty, x0, x1, tx);
    }
    __syncthreads();

    float s = 0.f, s2 = 0.f;
    for (int d = tid; d < D_; d += 256) {
        float v;
        if (d < C_)            v = pre_q[(size_t)m * C_ + d];
        else if (d < 2 * C_)   v = bf[d - C_];
        else if (d == 2 * C_)  v = cy;
        else if (d == 2*C_+1)  v = cx;
        else                   v = first_q[(size_t)m * C_ + (d - 2 * C_ - 2)];
        s += v; s2 += v * v;
    }
    block_reduce_2(s, s2, red);
    float mean = s / (float)D_;
    float var = s2 / (float)D_ - mean * mean;
    float inv = rsqrtf(var + EPS_);

    const float negLogDivD = -logf(10000.0f) / (float)D_;
    for (int d = tid; d < KPD_; d += 256) {
        if (d < D_) {
            float v;
            if (d < C_)            v = pre_q[(size_t)m * C_ + d];
            else if (d < 2 * C_)   v = bf[d - C_];
            else if (d == 2 * C_)  v = cy;
            else if (d == 2*C_+1)  v = cx;
            else                   v = first_q[(size_t)m * C_ + (d - 2 * C_ - 2)];
            float ln = ln_g[d] * (v - mean) * inv + ln_b[d];
            int kk = d >> 1;
            float ang = (float)n * expf((float)(2 * kk) * negLogDivD);
            float pe = (d & 1) ? cosf(ang) : sinf(ang);
            float val = ln + pe;
            tokens[(size_t)m * D_ + d] = val;
            tokens_bf[(size_t)m * KPD_ + d] = f2bf(val);
        } else {
            tokens_bf[(size_t)m * KPD_ + d] = 0;
        }
    }
}

// ------------------------------------------------ MFMA GEMM, split-K v2
// C[m,o] (+)= sum_{k chunk} A[m,k]*W[o,k] via fp32 atomicAdd. Each wave owns
// TWO o-strips (o0, o0+16) sharing A fragments; block covers 128 o. Explicit
// 2-deep software pipeline: chunk i+1's A/W loads issue before chunk i's
// MFMAs (VGPR ~200 -> 2 waves/SIMD, ~18 loads in flight per wave).
__global__ __launch_bounds__(256) void gemm_mfma_sk(
        const short* __restrict__ A, const float* __restrict__ Wf,
        const float* __restrict__ bias, float* __restrict__ Cout,
        int K, int KpA, int O, int KC) {
    int kc0 = blockIdx.y * KC;
    if (kc0 >= K) return;
    int kend = min(K, kc0 + KC);

    int lane = threadIdx.x & 63;
    int wave = threadIdx.x >> 6;
    int col  = lane & 15;
    int quad = lane >> 4;
    int o0 = blockIdx.x * 128 + wave * 32 + col;
    int o1 = o0 + 16;
    int oc0 = min(o0, O - 1), oc1 = min(o1, O - 1);

    const float* wrow0 = Wf + (size_t)oc0 * K + quad * 8;
    const float* wrow1 = Wf + (size_t)oc1 * K + quad * 8;
    const short* abase = A + (size_t)col * KpA + quad * 8;

    f32x4 acc0[10], acc1[10];
#pragma unroll
    for (int t = 0; t < 10; ++t)
#pragma unroll
        for (int r = 0; r < 4; ++r) { acc0[t][r] = 0.f; acc1[t][r] = 0.f; }

    int nfull = (kend - kc0) >> 5;
    bf16x8 aCur[10];
    float2 wCur[8];
    if (nfull > 0) {
#pragma unroll
        for (int t = 0; t < 10; ++t)
            aCur[t] = *(const bf16x8*)(abase + (size_t)t * 16 * KpA + kc0);
#pragma unroll
        for (int j = 0; j < 4; ++j) {
            wCur[j]     = *(const float2*)(wrow0 + kc0 + 2 * j);
            wCur[4 + j] = *(const float2*)(wrow1 + kc0 + 2 * j);
        }
    }
    for (int i = 0; i < nfull; ++i) {
        bf16x8 aNxt[10];
        float2 wNxt[8];
        if (i + 1 < nfull) {
            int kn = kc0 + (i + 1) * 32;
#pragma unroll
            for (int t = 0; t < 10; ++t)
                aNxt[t] = *(const bf16x8*)(abase + (size_t)t * 16 * KpA + kn);
#pragma unroll
            for (int j = 0; j < 4; ++j) {
                wNxt[j]     = *(const float2*)(wrow0 + kn + 2 * j);
                wNxt[4 + j] = *(const float2*)(wrow1 + kn + 2 * j);
            }
        }
        bf16x8 b0, b1;
#pragma unroll
        for (int j = 0; j < 4; ++j) {
            b0[2*j] = f2bf(wCur[j].x);     b0[2*j+1] = f2bf(wCur[j].y);
            b1[2*j] = f2bf(wCur[4+j].x);   b1[2*j+1] = f2bf(wCur[4+j].y);
        }
#pragma unroll
        for (int t = 0; t < 10; ++t) {
            acc0[t] = __builtin_amdgcn_mfma_f32_16x16x32_bf16(aCur[t], b0, acc0[t], 0, 0, 0);
            acc1[t] = __builtin_amdgcn_mfma_f32_16x16x32_bf16(aCur[t], b1, acc1[t], 0, 0, 0);
        }
#pragma unroll
        for (int t = 0; t < 10; ++t) aCur[t] = aNxt[t];
#pragma unroll
        for (int j = 0; j < 8; ++j) wCur[j] = wNxt[j];
    }
    int kmain = kc0 + nfull * 32;
    if (kmain < kend) {   // ragged tail (last split only); A is zero-padded
        bf16x8 b0, b1;
#pragma unroll
        for (int j = 0; j < 8; ++j) {
            int k = kmain + quad * 8 + j;
            b0[j] = (k < kend) ? f2bf(Wf[(size_t)oc0 * K + k]) : (short)0;
            b1[j] = (k < kend) ? f2bf(Wf[(size_t)oc1 * K + k]) : (short)0;
        }
#pragma unroll
        for (int t = 0; t < 10; ++t) {
            bf16x8 af = *(const bf16x8*)(abase + (size_t)t * 16 * KpA + kmain);
            acc0[t] = __builtin_amdgcn_mfma_f32_16x16x32_bf16(af, b0, acc0[t], 0, 0, 0);
            acc1[t] = __builtin_amdgcn_mfma_f32_16x16x32_bf16(af, b1, acc1[t], 0, 0, 0);
        }
    }
    if (o0 < O) {
        float bv = (blockIdx.y == 0) ? bias[o0] : 0.f;
#pragma unroll
        for (int t = 0; t < 10; ++t)
#pragma unroll
            for (int r = 0; r < 4; ++r)
                atomicAdd(&Cout[(size_t)(t * 16 + quad * 4 + r) * O + o0], acc0[t][r] + bv);
    }
    if (o1 < O) {
        float bv = (blockIdx.y == 0) ? bias[o1] : 0.f;
#pragma unroll
        for (int t = 0; t < 10; ++t)
#pragma unroll
            for (int r = 0; r < 4; ++r)
                atomicAdd(&Cout[(size_t)(t * 16 + quad * 4 + r) * O + o1], acc1[t][r] + bv);
    }
}

// ------------------------------------------------ relu + bf16 convert (ff1)
__global__ __launch_bounds__(256) void relu_cvt_kernel(const float* __restrict__ in,
                                                       short* __restrict__ out,
                                                       int n) {
    int i = blockIdx.x * 256 + threadIdx.x;
    if (i < n) out[i] = f2bf(fmaxf(in[i], 0.f));
}

// ---------------------------------------- qkv fp32 -> padded bf16 q/k/v
// q_bf,k_bf: [M_][KPD_]; v_bf: [B_][96][KPD_] (rows 80..95 pre-zeroed)
__global__ __launch_bounds__(256) void qkv_cvt_kernel(const float* __restrict__ qkv,
                                                      short* __restrict__ q_bf,
                                                      short* __restrict__ k_bf,
                                                      short* __restrict__ v_bf) {
    int m = blockIdx.x;
    int b = m / N_, q = m % N_;
    const float* src = qkv + (size_t)m * QKV_;
    for (int d = threadIdx.x; d < KPD_; d += 256) {
        short qv = (d < D_) ? f2bf(src[d])          : (short)0;
        short kv = (d < D_) ? f2bf(src[D_ + d])     : (short)0;
        short vv = (d < D_) ? f2bf(src[2 * D_ + d]) : (short)0;
        q_bf[(size_t)m * KPD_ + d] = qv;
        k_bf[(size_t)m * KPD_ + d] = kv;
        v_bf[((size_t)b * 96 + q) * KPD_ + d] = vv;
    }
}

// ------------------------------------------------ scores = Q·K^T via MFMA
// grid: b*25 + qt*5 + kt (50 blocks). 4 waves split the d-chunks; LDS reduce.
__global__ __launch_bounds__(256) void scores_mfma(const short* __restrict__ q_bf,
                                                   const short* __restrict__ k_bf,
                                                   float* __restrict__ sc) {
    int bi = blockIdx.x;
    int b = bi / 25, qt = (bi % 25) / 5, kt = bi % 5;
    int lane = threadIdx.x & 63, wave = threadIdx.x >> 6;
    int col = lane & 15, quad = lane >> 4;
    const short* qbase = q_bf + (size_t)(b * N_ + qt * 16 + col) * KPD_ + quad * 8;
    const short* kbase = k_bf + (size_t)(b * N_ + kt * 16 + col) * KPD_ + quad * 8;
    f32x4 acc;
#pragma unroll
    for (int r = 0; r < 4; ++r) acc[r] = 0.f;
    int c0 = wave * 25, c1 = min(97, c0 + 25);   // 97 chunks of 32 over KPD_
    for (int c = c0; c < c1; ++c) {
        bf16x8 af = *(const bf16x8*)(qbase + c * 32);
        bf16x8 bf8 = *(const bf16x8*)(kbase + c * 32);
        acc = __builtin_amdgcn_mfma_f32_16x16x32_bf16(af, bf8, acc, 0, 0, 0);
    }
    __shared__ f32x4 red[4][64];
    red[wave][lane] = acc;
    __syncthreads();
    if (threadIdx.x < 64) {
        f32x4 t = red[0][lane];
#pragma unroll
        for (int w = 1; w < 4; ++w)
#pragma unroll
            for (int r = 0; r < 4; ++r) t[r] += red[w][lane][r];
        float scale = rsqrtf((float)D_);
#pragma unroll
        for (int r = 0; r < 4; ++r)
            sc[(size_t)(b * N_ + qt * 16 + quad * 4 + r) * N_ + kt * 16 + col] = t[r] * scale;
    }
}

// ------------------------------------------------ softmax -> p_bf [M_][96]
__global__ __launch_bounds__(256) void softmax_kernel(const float* __restrict__ sc,
                                                      short* __restrict__ p_bf) {
    int m = blockIdx.x * 4 + (threadIdx.x >> 6);
    int lane = threadIdx.x & 63;
    const float* row = sc + (size_t)m * N_;
    float a = row[lane];
    float bv = (lane < 16) ? row[64 + lane] : -1e30f;
    float mx = wave_max(fmaxf(a, bv));
    mx = __shfl(mx, 0, 64);
    float e0 = expf(a - mx);
    float e1 = (lane < 16) ? expf(bv - mx) : 0.f;
    float sum = wave_sum(e0 + e1);
    sum = __shfl(sum, 0, 64);
    float rs = 1.0f / sum;
    p_bf[(size_t)m * 96 + lane] = f2bf(e0 * rs);
    if (lane < 32)
        p_bf[(size_t)m * 96 + 64 + lane] = (lane < 16) ? f2bf(e1 * rs) : (short)0;
}

// ------------------------------------------------ av = P·V via MFMA
// grid: b*49 + dgroup (98 blocks); wave w -> d-tile dgroup*4+w (194 tiles).
__global__ __launch_bounds__(256) void av_mfma(const short* __restrict__ p_bf,
                                               const short* __restrict__ v_bf,
                                               short* __restrict__ av_bf) {
    int bi = blockIdx.x;
    int b = bi / 49, g = bi % 49;
    int lane = threadIdx.x & 63, wave = threadIdx.x >> 6;
    int dtile = g * 4 + wave;
    if (dtile >= 194) return;          // no barriers below
    int d0 = dtile * 16;
    int col = lane & 15, quad = lane >> 4;
    const short* pbase = p_bf + (size_t)b * N_ * 96 + quad * 8;
    const short* vb = v_bf + (size_t)b * 96 * KPD_ + d0 + col;
    f32x4 acc[5];
#pragma unroll
    for (int t = 0; t < 5; ++t)
#pragma unroll
        for (int r = 0; r < 4; ++r) acc[t][r] = 0.f;
#pragma unroll
    for (int c = 0; c < 3; ++c) {      // K = 96 = 3 chunks of 32
        bf16x8 bf8;
#pragma unroll
        for (int j = 0; j < 8; ++j)
            bf8[j] = vb[(size_t)(c * 32 + quad * 8 + j) * KPD_];
#pragma unroll
        for (int t = 0; t < 5; ++t) {
            bf16x8 af = *(const bf16x8*)(pbase + (size_t)(t * 16 + col) * 96 + c * 32);
            acc[t] = __builtin_amdgcn_mfma_f32_16x16x32_bf16(af, bf8, acc[t], 0, 0, 0);
        }
    }
#pragma unroll
    for (int t = 0; t < 5; ++t)
#pragma unroll
        for (int r = 0; r < 4; ++r)
            av_bf[(size_t)(b * N_ + t * 16 + quad * 4 + r) * KPD_ + d0 + col] = f2bf(acc[t][r]);
}

// ---------------------------------------------------------------- layernorm
template <bool WF32>
__global__ __launch_bounds__(256) void ln_kernel(const float* __restrict__ xin,
                                                 const float* __restrict__ res,
                                                 const float* __restrict__ g,
                                                 const float* __restrict__ bta,
                                                 float* __restrict__ outf,
                                                 short* __restrict__ outb) {
    int m = blockIdx.x;
    int tid = threadIdx.x;
    __shared__ float red[10];
    const float* xr = xin + (size_t)m * D_;
    const float* rr = res + (size_t)m * D_;
    float s = 0.f, s2 = 0.f;
    for (int d = tid; d < D_; d += 256) {
        float v = xr[d] + rr[d];
        s += v; s2 += v * v;
    }
    block_reduce_2(s, s2, red);
    float mean = s / (float)D_;
    float var = s2 / (float)D_ - mean * mean;
    float inv = rsqrtf(var + EPS_);
    for (int d = tid; d < KPD_; d += 256) {
        if (d < D_) {
            float v = xr[d] + rr[d];
            float y = g[d] * (v - mean) * inv + bta[d];
            if (WF32) outf[(size_t)m * D_ + d] = y;
            outb[(size_t)m * KPD_ + d] = f2bf(y);
        } else {
            outb[(size_t)m * KPD_ + d] = 0;
        }
    }
}

// ---------------------------------------------------------------- update
__global__ __launch_bounds__(256) void update_kernel(const float* __restrict__ outb,
                                                     float* __restrict__ curr,
                                                     float* __restrict__ pre_q,
                                                     float* __restrict__ results) {
    int m = blockIdx.x;
    int tid = threadIdx.x;
    for (int c = tid; c < C_; c += 256)
        pre_q[(size_t)m * C_ + c] += outb[(size_t)m * OD_ + c];
    if (tid < 2) {
        float nc = curr[m * 2 + tid] + outb[(size_t)m * OD_ + C_ + tid];
        nc = fminf(fmaxf(nc, 0.f), 223.f);
        curr[m * 2 + tid] = nc;
        results[m * 2 + tid] = nc;
    }
}

// ---------------------------------------------------------------- launch
extern "C" void kernel_launch(void* const* d_in, const int* in_sizes, int n_in,
                              void* d_out, int out_size, void* d_ws, size_t ws_size,
                              hipStream_t stream) {
    const float* pre_f   = (const float*)d_in[0];
    const float* curr_f  = (const float*)d_in[1];
    const float* first_f = (const float*)d_in[2];
    const int*   prev_b  = (const int*)d_in[3];
    const int*   first_b = (const int*)d_in[4];
    const float* ln_g    = (const float*)d_in[5];
    const float* ln_b    = (const float*)d_in[6];
    const float* ipw     = (const float*)d_in[7];
    const float* ipb     = (const float*)d_in[8];
    const float* opw     = (const float*)d_in[9];
    const float* opb     = (const float*)d_in[10];
    const float* n1g     = (const float*)d_in[11];
    const float* n1b     = (const float*)d_in[12];
    const float* l1w     = (const float*)d_in[13];
    const float* l1b     = (const float*)d_in[14];
    const float* l2w     = (const float*)d_in[15];
    const float* l2b     = (const float*)d_in[16];
    const float* n2g     = (const float*)d_in[17];
    const float* n2b     = (const float*)d_in[18];
    const float* ow      = (const float*)d_in[19];
    const float* ob      = (const float*)d_in[20];
    float* outp = (float*)d_out;

    float* wf = (float*)d_ws;
    size_t off = 0;
    int*   fb_al   = (int*)(wf + off); off += 320;
    float* curr    = wf + off;         off += 320;
    float* pre_q   = wf + off;         off += (size_t)M_ * C_;
    float* first_q = wf + off;         off += (size_t)M_ * C_;
    float* tokens  = wf + off;         off += (size_t)M_ * D_;
    float* qkv     = wf + off;         off += (size_t)M_ * QKV_;
    float* aout    = wf + off;         off += (size_t)M_ * D_;
    float* xbuf    = wf + off;         off += (size_t)M_ * D_;
    float* ff1f    = wf + off;         off += (size_t)M_ * DFF_;
    float* ffout   = wf + off;         off += (size_t)M_ * D_;
    float* outb    = wf + off;         off += (size_t)M_ * OD_;
    float* sc      = wf + off;         off += (size_t)M_ * N_;
    short* tokens_bf = (short*)(wf + off); off += (size_t)M_ * KPD_ / 2;
    short* x_bf      = (short*)(wf + off); off += (size_t)M_ * KPD_ / 2;
    short* x2_bf     = (short*)(wf + off); off += (size_t)M_ * KPD_ / 2;
    short* av_bf     = (short*)(wf + off); off += (size_t)M_ * KPD_ / 2;
    short* ff1_bf    = (short*)(wf + off); off += (size_t)M_ * DFF_ / 2;
    short* q_bf      = (short*)(wf + off); off += (size_t)M_ * KPD_ / 2;
    short* k_bf      = (short*)(wf + off); off += (size_t)M_ * KPD_ / 2;
    short* v_bf      = (short*)(wf + off); off += (size_t)B_ * 96 * KPD_ / 2;
    short* p_bf      = (short*)(wf + off); off += (size_t)M_ * 96 / 2;
    (void)ws_size; (void)in_sizes; (void)n_in; (void)out_size;

    hipLaunchKernelGGL(align_kernel, dim3(B_), dim3(128), 0, stream,
                       prev_b, first_b, fb_al);
    hipLaunchKernelGGL(gather_init_kernel, dim3(M_), dim3(256), 0, stream,
                       pre_f, first_f, prev_b, fb_al, pre_q, first_q, curr);
    // zero v_bf once (pad rows 80..95 must be 0; real rows overwritten each iter)
    hipMemsetAsync(v_bf, 0, (size_t)B_ * 96 * KPD_ * 2, stream);

    for (int it = 0; it < 3; ++it) {
        hipMemsetAsync(qkv,   0, (size_t)M_ * QKV_ * 4, stream);
        hipMemsetAsync(aout,  0, (size_t)M_ * D_   * 4, stream);
        hipMemsetAsync(ff1f,  0, (size_t)M_ * DFF_ * 4, stream);
        hipMemsetAsync(ffout, 0, (size_t)M_ * D_   * 4, stream);
        hipMemsetAsync(outb,  0, (size_t)M_ * OD_  * 4, stream);

        hipLaunchKernelGGL(tokens_kernel, dim3(M_), dim3(256), 0, stream,
                           curr_f, pre_q, first_q, curr, ln_g, ln_b, tokens, tokens_bf);
        // qkv: O=9222 -> 73 o-blocks x S=6 (KC=544) = 438 blocks
        hipLaunchKernelGGL(gemm_mfma_sk, dim3(73, 6), dim3(256), 0, stream,
                           tokens_bf, ipw, ipb, qkv, D_, KPD_, QKV_, 544);
        hipLaunchKernelGGL(qkv_cvt_kernel, dim3(M_), dim3(256), 0, stream,
                           qkv, q_bf, k_bf, v_bf);
        hipLaunchKernelGGL(scores_mfma, dim3(50), dim3(256), 0, stream,
                           q_bf, k_bf, sc);
        hipLaunchKernelGGL(softmax_kernel, dim3(40), dim3(256), 0, stream,
                           sc, p_bf);
        hipLaunchKernelGGL(av_mfma, dim3(98), dim3(256), 0, stream,
                           p_bf, v_bf, av_bf);
        // out-proj: O=3074 -> 25 x S=10 (KC=320) = 250 blocks
        hipLaunchKernelGGL(gemm_mfma_sk, dim3(25, 10), dim3(256), 0, stream,
                           av_bf, opw, opb, aout, D_, KPD_, D_, 320);
        hipLaunchKernelGGL((ln_kernel<true>), dim3(M_), dim3(256), 0, stream,
                           tokens, aout, n1g, n1b, xbuf, x_bf);
        // ff1: O=2048 -> 16 x S=17 (KC=192) = 272 blocks
        hipLaunchKernelGGL(gemm_mfma_sk, dim3(16, 17), dim3(256), 0, stream,
                           x_bf, l1w, l1b, ff1f, D_, KPD_, DFF_, 192);
        hipLaunchKernelGGL(relu_cvt_kernel, dim3((M_ * DFF_ + 255) / 256), dim3(256), 0, stream,
                           ff1f, ff1_bf, M_ * DFF_);
        // ff2: K=2048, O=3074 -> 25 x S=11 (KC=192) = 275 blocks
        hipLaunchKernelGGL(gemm_mfma_sk, dim3(25, 11), dim3(256), 0, stream,
                           ff1_bf, l2w, l2b, ffout, DFF_, DFF_, D_, 192);
        hipLaunchKernelGGL((ln_kernel<false>), dim3(M_), dim3(256), 0, stream,
                           xbuf, ffout, n2g, n2b, (float*)nullptr, x2_bf);
        // head: O=1026 -> 9 x S=13 (KC=256) = 117 blocks
        hipLaunchKernelGGL(gemm_mfma_sk, dim3(9, 13), dim3(256), 0, stream,
                           x2_bf, ow, ob, outb, D_, KPD_, OD_, 256);
        hipLaunchKernelGGL(update_kernel, dim3(M_), dim3(256), 0, stream,
                           outb, curr, pre_q, outp + (size_t)it * M_ * 2);
    }
}